// Round 12
// baseline (29.988 us; speedup 1.0000x reference)
//
#include <hip/hip_runtime.h>
#include <math.h>

#define NN 16
#define GG 4096
#define XSTR 52           // packed feature stride: 52*i mod 32 hits 8 distinct bank-quads
#define NWG (GG / 2)      // 2048 blocks x 128 threads; wave w owns grid point g0+w

// ---- DPP helpers (quad_perm = VALU cross-lane, no DS pipe) ----
template <int CTRL>
__device__ __forceinline__ float dppf(float x) {
    return __builtin_bit_cast(float, __builtin_amdgcn_mov_dpp(
        __builtin_bit_cast(int, x), CTRL, 0xF, 0xF, true));
}
__device__ __forceinline__ float qb(float x, int L) {
    switch (L) {
        case 0:  return dppf<0x00>(x);
        case 1:  return dppf<0x55>(x);
        case 2:  return dppf<0xAA>(x);
        default: return dppf<0xFF>(x);
    }
}
__device__ __forceinline__ float qsum(float x) {
    x += dppf<0xB1>(x);
    x += dppf<0x4E>(x);
    return x;
}
__device__ __forceinline__ void bcast_row(float out[8], const float r0[8],
                                          const float r1[8], int k) {
#pragma unroll
    for (int c = 0; c < 8; ++c) {
        float s = (k < 4) ? r0[c] : r1[c];
        out[c] = qb(s, k & 3);
    }
}
__device__ __forceinline__ float sel4(float a, float b, float c, float d, int k) {
    return (k == 0) ? a : (k == 1) ? b : (k == 2) ? c : d;
}
__device__ __forceinline__ float sel_lo(const float r[8], int q) {
    return sel4(r[0], r[1], r[2], r[3], q);
}
__device__ __forceinline__ float sel_hi(const float r[8], int q) {
    return sel4(r[4], r[5], r[6], r[7], q);
}
__device__ __forceinline__ void ld_row(float r[8], const float* p) {
    float4 x = *(const float4*)p, y = *(const float4*)(p + 4);
    r[0] = x.x; r[1] = x.y; r[2] = x.z; r[3] = x.w;
    r[4] = y.x; r[5] = y.y; r[6] = y.z; r[7] = y.w;
}
__device__ __forceinline__ float dot8(const float a[8], const float b[8]) {
    float s = a[0] * b[0];
    s = fmaf(a[1], b[1], s); s = fmaf(a[2], b[2], s);
    s = fmaf(a[3], b[3], s); s = fmaf(a[4], b[4], s);
    s = fmaf(a[5], b[5], s); s = fmaf(a[6], b[6], s);
    s = fmaf(a[7], b[7], s);
    return s;
}

// 4-lane cooperative Gauss-Jordan (inverse + det). Lane q holds rows q, q+4.
__device__ __forceinline__ float gj4(float r0[8], float r1[8], int q) {
    float pp = 1.0f;
#pragma unroll
    for (int k = 0; k < 8; ++k) {
        float Mk[8];
        bcast_row(Mk, r0, r1, k);
        float p = Mk[k];
        pp *= p;
        float ip = 1.0f / p;
        bool own0 = (k < 4) && (q == k);
        bool own1 = (k >= 4) && (q == k - 4);
        float m0 = -(own0 ? -1.0f : r0[k]) * ip;
        float m1 = -(own1 ? -1.0f : r1[k]) * ip;
#pragma unroll
        for (int c = 0; c < 8; ++c) {
            float b0 = own0 ? 0.0f : r0[c];
            float b1 = own1 ? 0.0f : r1[c];
            r0[c] = fmaf(m0, Mk[c], b0);
            r1[c] = fmaf(m1, Mk[c], b1);
        }
        r0[k] = m0;
        r1[k] = m1;
    }
    return pp;
}

// 4-lane cooperative LU determinant (det only, destroys rows).
__device__ __forceinline__ float ludet4(float r0[8], float r1[8], int q) {
    float pp = 1.0f;
#pragma unroll
    for (int k = 0; k < 8; ++k) {
        float Mk[8];
#pragma unroll
        for (int c = k; c < 8; ++c) {
            float s = (k < 4) ? r0[c] : r1[c];
            Mk[c] = qb(s, k & 3);
        }
        float p = Mk[k];
        pp *= p;
        float ip = 1.0f / p;
        float f0 = (q > k) ? r0[k] * ip : 0.f;
        float f1 = (q + 4 > k) ? r1[k] * ip : 0.f;
#pragma unroll
        for (int c = k + 1; c < 8; ++c) {
            r0[c] = fmaf(-f0, Mk[c], r0[c]);
            r1[c] = fmaf(-f1, Mk[c], r1[c]);
        }
    }
    return pp;
}

__global__ __launch_bounds__(128) void pairkl_kernel(
    const float* __restrict__ omega, const float* __restrict__ links,
    const float* __restrict__ mu, const float* __restrict__ sigma,
    float* __restrict__ out) {
    // Packed symmetric features, wave-private slices (no cross-wave sharing).
    // x' = [diagX(8), 2*upperX(28), u(8), a_i, 1, 0..]   (52-stride)
    // y' = [diagP(8),   upperP(28), -2w(8), 1, s_j, 0..]
    __shared__ __align__(16) float sh_x[2][NN][XSTR];
    __shared__ __align__(16) float sh_y[2][NN][XSTR];

    const int bid  = blockIdx.x;
    const int work = (bid & 7) * (NWG / 8) + (bid >> 3);  // XCD-bijective swizzle
    const int t    = threadIdx.x;
    const int w    = t >> 6;
    const int g    = work * 2 + w;
    const int lane = t & 63;
    const int item = lane >> 2;
    const int q    = lane & 3;
    const int mb   = (item * GG + g) * 64;
    const float* l0p = links + ((item * 2 + 0) * GG + g) * 64;
    const float* l1p = links + ((item * 2 + 1) * GG + g) * 64;

    float mq[8];
    ld_row(mq, mu + (item * GG + g) * 8);

    // ================= A-part =================
    float R0[8], R1[8];  // T rows -> Winv rows
    {
        float o0[8], o1[8];
        ld_row(o0, omega + mb + q * 8);
        ld_row(o1, omega + mb + (q + 4) * 8);
#pragma unroll
        for (int c = 0; c < 8; ++c) { R0[c] = 0.f; R1[c] = 0.f; }
        // T = omega @ V, V row b streamed from links (quad-uniform addr, L1)
#pragma unroll
        for (int b = 0; b < 8; ++b) {
            float la[8], lb[8];
            ld_row(la, l0p + b * 8);
            ld_row(lb, l1p + b * 8);
#pragma unroll
            for (int c = 0; c < 8; ++c) {
                float vb = la[c] + lb[c] - ((c == b) ? 1.f : 0.f);
                R0[c] = fmaf(o0[b], vb, R0[c]);
                R1[c] = fmaf(o1[b], vb, R1[c]);
            }
        }
    }  // omega rows dead (B reloads them L1-hot)
    float ldV;
    {
        // reload own V rows (L1-hot) for the determinant
        float v0[8], v1[8], la[8], lb[8];
        ld_row(la, l0p + q * 8);
        ld_row(lb, l1p + q * 8);
#pragma unroll
        for (int c = 0; c < 8; ++c) v0[c] = la[c] + lb[c] - ((c == q) ? 1.f : 0.f);
        ld_row(la, l0p + (q + 4) * 8);
        ld_row(lb, l1p + (q + 4) * 8);
#pragma unroll
        for (int c = 0; c < 8; ++c) v1[c] = la[c] + lb[c] - ((c == q + 4) ? 1.f : 0.f);
        ldV = logf(fabsf(ludet4(v0, v1, q)));
    }
    float ldT = logf(fabsf(gj4(R0, R1, q)));  // R = Winv
    // Z = Winv @ sigma, sigma rows streamed from global (L1)
    float Z0[8], Z1[8];
#pragma unroll
    for (int c = 0; c < 8; ++c) { Z0[c] = 0.f; Z1[c] = 0.f; }
#pragma unroll
    for (int b = 0; b < 8; ++b) {
        float sr[8];
        ld_row(sr, sigma + mb + b * 8);
#pragma unroll
        for (int c = 0; c < 8; ++c) {
            Z0[c] = fmaf(R0[b], sr[c], Z0[c]);
            Z1[c] = fmaf(R1[b], sr[c], Z1[c]);
        }
    }
    float u_lo = dot8(R0, mq), u_hi = dot8(R1, mq);
    float uf[8];
#pragma unroll
    for (int c = 0; c < 4; ++c) { uf[c] = qb(u_lo, c); uf[c + 4] = qb(u_hi, c); }
    {
        // X rows q, q+4:  X = Z Winv^T + u u^T   (symmetric)
        float X0[8], X1[8];
#pragma unroll
        for (int c = 0; c < 8; ++c) {
            float Wc[8]; bcast_row(Wc, R0, R1, c);
            X0[c] = fmaf(u_lo, uf[c], dot8(Z0, Wc));
            X1[c] = fmaf(u_hi, uf[c], dot8(Z1, Wc));
        }
        // packed write: diag + doubled upper triangle (rows q and q+4)
        float* xb = &sh_x[w][item][0];
        xb[q]     = sel4(X0[0], X0[1], X0[2], X0[3], q);
        xb[q + 4] = sel4(X1[4], X1[5], X1[6], X1[7], q);
        const int basea = 7 + 6 * q - ((q * (q - 1)) >> 1);          // off(q,b)-b
        const int a2 = q + 4;
        const int baseb = 7 + 6 * a2 - ((a2 * (a2 - 1)) >> 1);       // off(q+4,b)-b
#pragma unroll
        for (int b = 1; b < 8; ++b)
            if (b > q) xb[basea + b] = 2.f * X0[b];
#pragma unroll
        for (int b = 5; b < 8; ++b)
            if (b > a2) xb[baseb + b] = 2.f * X1[b];
        if (q == 0) {
            *(float4*)&xb[36] = make_float4(uf[0], uf[1], uf[2], uf[3]);
            *(float4*)&xb[40] = make_float4(uf[4], uf[5], uf[6], uf[7]);
        }
    }

    // ================= B-part =================
    float s0[8], s1[8];
    ld_row(s0, sigma + mb + q * 8);       // L1-hot
    ld_row(s1, sigma + mb + (q + 4) * 8);
    float ld1 = logf(fabsf(gj4(s0, s1, q)));      // s = siginv
    float mql = sel_lo(mq, q), mqh = sel_hi(mq, q);
    float cc  = qsum(dot8(s0, mq) * mql + dot8(s1, mq) * mqh);
    // U = siginv @ omega, omega rows streamed from global (L1-hot)
    float U0[8], U1[8];
#pragma unroll
    for (int c = 0; c < 8; ++c) { U0[c] = 0.f; U1[c] = 0.f; }
#pragma unroll
    for (int b = 0; b < 8; ++b) {
        float orow[8];
        ld_row(orow, omega + mb + b * 8);
#pragma unroll
        for (int c = 0; c < 8; ++c) {
            U0[c] = fmaf(s0[b], orow[c], U0[c]);
            U1[c] = fmaf(s1[b], orow[c], U1[c]);
        }
    }
    float wf[8];
#pragma unroll
    for (int c = 0; c < 8; ++c) wf[c] = qsum(fmaf(mql, U0[c], mqh * U1[c]));
    {
        // P rows q, q+4:  P = omega^T U (symmetric); omega columns from global
        float oc0[8], oc1[8];
#pragma unroll
        for (int a = 0; a < 8; ++a) {
            oc0[a] = omega[mb + a * 8 + q];
            oc1[a] = omega[mb + a * 8 + q + 4];
        }
        float P0[8], P1[8];
#pragma unroll
        for (int c = 0; c < 8; ++c) { P0[c] = 0.f; P1[c] = 0.f; }
#pragma unroll
        for (int a = 0; a < 8; ++a) {
            float Ua[8]; bcast_row(Ua, U0, U1, a);
#pragma unroll
            for (int c = 0; c < 8; ++c) {
                P0[c] = fmaf(oc0[a], Ua[c], P0[c]);
                P1[c] = fmaf(oc1[a], Ua[c], P1[c]);
            }
        }
        float* yb = &sh_y[w][item][0];
        yb[q]     = sel4(P0[0], P0[1], P0[2], P0[3], q);
        yb[q + 4] = sel4(P1[4], P1[5], P1[6], P1[7], q);
        const int basea = 7 + 6 * q - ((q * (q - 1)) >> 1);
        const int a2 = q + 4;
        const int baseb = 7 + 6 * a2 - ((a2 * (a2 - 1)) >> 1);
#pragma unroll
        for (int b = 1; b < 8; ++b)
            if (b > q) yb[basea + b] = P0[b];
#pragma unroll
        for (int b = 5; b < 8; ++b)
            if (b > a2) yb[baseb + b] = P1[b];
        if (q == 0) {
            float ldo = ldT - ldV;
            float a_i = 2.f * ldT - ld1;
            float s_j = ld1 - 2.f * ldo + cc - 8.0f;
            *(float4*)&yb[36] =
                make_float4(-2.f * wf[0], -2.f * wf[1], -2.f * wf[2], -2.f * wf[3]);
            *(float4*)&yb[40] =
                make_float4(-2.f * wf[4], -2.f * wf[5], -2.f * wf[6], -2.f * wf[7]);
            *(float4*)&yb[44] = make_float4(1.f, s_j, 0.f, 0.f);
            *(float4*)&sh_x[w][item][44] = make_float4(a_i, 1.f, 0.f, 0.f);
        }
    }
    // wave-private LDS slice: program-order DS completion makes the writes
    // visible to this wave's reads; fence stops compile-time reordering.
    asm volatile("" ::: "memory");

    // ---- Phase 2: E[i,j] = 0.5 * dot48(x_i, y_j); 2i x 2j per lane ----
    {
        const int i0 = lane >> 3, j0 = lane & 7;
        const int i1 = i0 + 8, j1 = j0 + 8;
        const float4* x0 = (const float4*)&sh_x[w][i0][0];
        const float4* x1 = (const float4*)&sh_x[w][i1][0];
        const float4* y0 = (const float4*)&sh_y[w][j0][0];
        const float4* y1 = (const float4*)&sh_y[w][j1][0];
        float d00 = 0.f, d01 = 0.f, d10 = 0.f, d11 = 0.f;
#pragma unroll
        for (int k = 0; k < 12; ++k) {  // 48 floats
            float4 a0 = x0[k], a1 = x1[k], b0 = y0[k], b1 = y1[k];
            d00 = fmaf(a0.x, b0.x, d00); d00 = fmaf(a0.y, b0.y, d00);
            d00 = fmaf(a0.z, b0.z, d00); d00 = fmaf(a0.w, b0.w, d00);
            d01 = fmaf(a0.x, b1.x, d01); d01 = fmaf(a0.y, b1.y, d01);
            d01 = fmaf(a0.z, b1.z, d01); d01 = fmaf(a0.w, b1.w, d01);
            d10 = fmaf(a1.x, b0.x, d10); d10 = fmaf(a1.y, b0.y, d10);
            d10 = fmaf(a1.z, b0.z, d10); d10 = fmaf(a1.w, b0.w, d10);
            d11 = fmaf(a1.x, b1.x, d11); d11 = fmaf(a1.y, b1.y, d11);
            d11 = fmaf(a1.z, b1.z, d11); d11 = fmaf(a1.w, b1.w, d11);
        }
        const bool dg = (i0 == j0);
        out[(i0 * NN + j0) * GG + g] = dg ? 0.f : 0.5f * d00;
        out[(i0 * NN + j1) * GG + g] = 0.5f * d01;
        out[(i1 * NN + j0) * GG + g] = 0.5f * d10;
        out[(i1 * NN + j1) * GG + g] = dg ? 0.f : 0.5f * d11;
    }
}

extern "C" void kernel_launch(void* const* d_in, const int* in_sizes, int n_in,
                              void* d_out, int out_size, void* d_ws, size_t ws_size,
                              hipStream_t stream) {
    const float* omega = (const float*)d_in[0];
    const float* links = (const float*)d_in[1];
    const float* mu    = (const float*)d_in[2];
    const float* sigma = (const float*)d_in[3];
    float* out = (float*)d_out;
    hipLaunchKernelGGL(pairkl_kernel, dim3(NWG), dim3(128), 0, stream,
                       omega, links, mu, sigma, out);
}

// Round 13
// 26.623 us; speedup vs baseline: 1.1264x; 1.1264x over previous
//
#include <hip/hip_runtime.h>
#include <math.h>

#define NN 16
#define GG 4096
#define STR 76            // feature-vector stride (floats)
#define SSTR 68           // sigma stage stride (floats)
#define NWG GG            // 4096 blocks, 1 wave per block, 1 grid point per wave

#define LN2 0.6931471805599453f

// fast hardware ops (1 ULP) — precise libm versions cost ~10 serialized VALU each
__device__ __forceinline__ float frcp(float x) { return __builtin_amdgcn_rcpf(x); }
__device__ __forceinline__ float flogabs(float x) {
    return __builtin_amdgcn_logf(fabsf(x)) * LN2;
}

// ---- DPP helpers (quad_perm = VALU cross-lane, no DS pipe) ----
template <int CTRL>
__device__ __forceinline__ float dppf(float x) {
    return __builtin_bit_cast(float, __builtin_amdgcn_mov_dpp(
        __builtin_bit_cast(int, x), CTRL, 0xF, 0xF, true));
}
__device__ __forceinline__ float qb(float x, int L) {
    switch (L) {
        case 0:  return dppf<0x00>(x);
        case 1:  return dppf<0x55>(x);
        case 2:  return dppf<0xAA>(x);
        default: return dppf<0xFF>(x);
    }
}
__device__ __forceinline__ float qsum(float x) {
    x += dppf<0xB1>(x);  // perm[1,0,3,2]
    x += dppf<0x4E>(x);  // perm[2,3,0,1]
    return x;
}
__device__ __forceinline__ void bcast_row(float out[8], const float r0[8],
                                          const float r1[8], int k) {
#pragma unroll
    for (int c = 0; c < 8; ++c) {
        float s = (k < 4) ? r0[c] : r1[c];
        out[c] = qb(s, k & 3);
    }
}
__device__ __forceinline__ float sel_lo(const float r[8], int q) {
    return (q == 0) ? r[0] : (q == 1) ? r[1] : (q == 2) ? r[2] : r[3];
}
__device__ __forceinline__ float sel_hi(const float r[8], int q) {
    return (q == 0) ? r[4] : (q == 1) ? r[5] : (q == 2) ? r[6] : r[7];
}
__device__ __forceinline__ void ld_row(float r[8], const float* p) {
    float4 x = *(const float4*)p, y = *(const float4*)(p + 4);
    r[0] = x.x; r[1] = x.y; r[2] = x.z; r[3] = x.w;
    r[4] = y.x; r[5] = y.y; r[6] = y.z; r[7] = y.w;
}
__device__ __forceinline__ void st_row(float* p, const float r[8]) {
    *(float4*)p       = make_float4(r[0], r[1], r[2], r[3]);
    *(float4*)(p + 4) = make_float4(r[4], r[5], r[6], r[7]);
}
__device__ __forceinline__ float dot8(const float a[8], const float b[8]) {
    float s = a[0] * b[0];
    s = fmaf(a[1], b[1], s); s = fmaf(a[2], b[2], s);
    s = fmaf(a[3], b[3], s); s = fmaf(a[4], b[4], s);
    s = fmaf(a[5], b[5], s); s = fmaf(a[6], b[6], s);
    s = fmaf(a[7], b[7], s);
    return s;
}

// 4-lane cooperative Gauss-Jordan (full inverse + det). Lane q holds rows
// q (r0), q+4 (r1). No pivoting (matrices are I+eps or SPD).
__device__ __forceinline__ float gj4(float r0[8], float r1[8], int q) {
    float pp = 1.0f;
#pragma unroll
    for (int k = 0; k < 8; ++k) {
        float Mk[8];
        bcast_row(Mk, r0, r1, k);
        float p = Mk[k];
        pp *= p;
        float ip = frcp(p);
        bool own0 = (k < 4) && (q == k);
        bool own1 = (k >= 4) && (q == k - 4);
        float m0 = -(own0 ? -1.0f : r0[k]) * ip;
        float m1 = -(own1 ? -1.0f : r1[k]) * ip;
#pragma unroll
        for (int c = 0; c < 8; ++c) {
            float b0 = own0 ? 0.0f : r0[c];
            float b1 = own1 ? 0.0f : r1[c];
            r0[c] = fmaf(m0, Mk[c], b0);
            r1[c] = fmaf(m1, Mk[c], b1);
        }
        r0[k] = m0;
        r1[k] = m1;
    }
    return pp;
}

// 4-lane cooperative LU determinant (det only, destroys rows). Partial
// broadcast: only columns >= k needed. No pivoting.
__device__ __forceinline__ float ludet4(float r0[8], float r1[8], int q) {
    float pp = 1.0f;
#pragma unroll
    for (int k = 0; k < 8; ++k) {
        float Mk[8];
#pragma unroll
        for (int c = k; c < 8; ++c) {
            float s = (k < 4) ? r0[c] : r1[c];
            Mk[c] = qb(s, k & 3);
        }
        float p = Mk[k];
        pp *= p;
        float ip = frcp(p);
        float f0 = (q > k) ? r0[k] * ip : 0.f;
        float f1 = (q + 4 > k) ? r1[k] * ip : 0.f;
#pragma unroll
        for (int c = k + 1; c < 8; ++c) {
            r0[c] = fmaf(-f0, Mk[c], r0[c]);
            r1[c] = fmaf(-f1, Mk[c], r1[c]);
        }
    }
    return pp;
}

__global__ __launch_bounds__(64) void pairkl_kernel(
    const float* __restrict__ omega, const float* __restrict__ links,
    const float* __restrict__ mu, const float* __restrict__ sigma,
    float* __restrict__ out) {
    __shared__ __align__(16) float sh_x[NN][STR];
    __shared__ __align__(16) float sh_y[NN][STR];
    // sigma stage overlaid on sh_y (15*68+64 = 1084 <= 1216 floats): every
    // sh_s read precedes every sh_y write in the single wave's program order,
    // and sh_s aliases sh_y so the compiler cannot reorder them.
    float* sh_s = &sh_y[0][0];  // layout [item][SSTR]

    const int bid  = blockIdx.x;
    const int g    = (bid & 7) * (NWG / 8) + (bid >> 3);  // XCD-bijective swizzle
    const int lane = threadIdx.x;
    const int item = lane >> 2;
    const int q    = lane & 3;
    const int mb   = (item * GG + g) * 64;

    // ---- Loads: V (from links) and omega to regs; sigma staged to LDS ----
    float v0[8], v1[8], o0[8], o1[8], mq[8];
    {
        const float* l0p = links + ((item * 2 + 0) * GG + g) * 64;
        const float* l1p = links + ((item * 2 + 1) * GG + g) * 64;
        float la[8], lb[8];
        ld_row(la, l0p + q * 8);
        ld_row(lb, l1p + q * 8);
#pragma unroll
        for (int c = 0; c < 8; ++c) v0[c] = la[c] + lb[c] - ((c == q) ? 1.f : 0.f);
        ld_row(la, l0p + (q + 4) * 8);
        ld_row(lb, l1p + (q + 4) * 8);
#pragma unroll
        for (int c = 0; c < 8; ++c) v1[c] = la[c] + lb[c] - ((c == q + 4) ? 1.f : 0.f);
    }
    ld_row(o0, omega + mb + q * 8);
    ld_row(o1, omega + mb + (q + 4) * 8);
    {
        float sa[8], sb[8];
        ld_row(sa, sigma + mb + q * 8);
        ld_row(sb, sigma + mb + (q + 4) * 8);
        st_row(&sh_s[item * SSTR + q * 8], sa);
        st_row(&sh_s[item * SSTR + (q + 4) * 8], sb);
    }
    ld_row(mq, mu + (item * GG + g) * 8);

    // ---- A-part ----
    float R0[8], R1[8];  // T then Winv
#pragma unroll
    for (int c = 0; c < 8; ++c) { R0[c] = 0.f; R1[c] = 0.f; }
#pragma unroll
    for (int b = 0; b < 8; ++b) {
        float Vb[8]; bcast_row(Vb, v0, v1, b);
#pragma unroll
        for (int c = 0; c < 8; ++c) {
            R0[c] = fmaf(o0[b], Vb[c], R0[c]);
            R1[c] = fmaf(o1[b], Vb[c], R1[c]);
        }
    }
    float ldV = flogabs(ludet4(v0, v1, q));   // destroys v (dead after T)
    float ldT = flogabs(gj4(R0, R1, q));      // R = Winv
    // Z = Winv @ sigma, sigma rows broadcast from LDS
    float Z0[8], Z1[8];
#pragma unroll
    for (int c = 0; c < 8; ++c) { Z0[c] = 0.f; Z1[c] = 0.f; }
#pragma unroll
    for (int b = 0; b < 8; ++b) {
        float sr[8]; ld_row(sr, &sh_s[item * SSTR + b * 8]);
#pragma unroll
        for (int c = 0; c < 8; ++c) {
            Z0[c] = fmaf(R0[b], sr[c], Z0[c]);
            Z1[c] = fmaf(R1[b], sr[c], Z1[c]);
        }
    }
    float u_lo = dot8(R0, mq), u_hi = dot8(R1, mq);
    float uf[8];
#pragma unroll
    for (int c = 0; c < 4; ++c) { uf[c] = qb(u_lo, c); uf[c + 4] = qb(u_hi, c); }
    // X = Z Winv^T + u u^T   (reuse v regs for X rows)
#pragma unroll
    for (int c = 0; c < 8; ++c) {
        float Wc[8]; bcast_row(Wc, R0, R1, c);
        v0[c] = fmaf(u_lo, uf[c], dot8(Z0, Wc));
        v1[c] = fmaf(u_hi, uf[c], dot8(Z1, Wc));
    }
    st_row(&sh_x[item][q * 8], v0);
    st_row(&sh_x[item][(q + 4) * 8], v1);

    // ---- B-part ----
    float s0[8], s1[8];
    ld_row(s0, &sh_s[item * SSTR + q * 8]);       // reload sigma (last sh_s read)
    ld_row(s1, &sh_s[item * SSTR + (q + 4) * 8]);
    float ld1 = flogabs(gj4(s0, s1, q));          // s = siginv
    float mql = sel_lo(mq, q), mqh = sel_hi(mq, q);
    float cc  = qsum(dot8(s0, mq) * mql + dot8(s1, mq) * mqh);
    // U = siginv @ omega (bcast omega rows; siginv lane-local)
    float U0[8], U1[8];
#pragma unroll
    for (int c = 0; c < 8; ++c) { U0[c] = 0.f; U1[c] = 0.f; }
#pragma unroll
    for (int b = 0; b < 8; ++b) {
        float Ob[8]; bcast_row(Ob, o0, o1, b);
#pragma unroll
        for (int c = 0; c < 8; ++c) {
            U0[c] = fmaf(s0[b], Ob[c], U0[c]);
            U1[c] = fmaf(s1[b], Ob[c], U1[c]);
        }
    }
    // w[c] = sum_a U[a,c] mu[a]  (quad reduction per column)
    float wf[8];
#pragma unroll
    for (int c = 0; c < 8; ++c) wf[c] = qsum(fmaf(mql, U0[c], mqh * U1[c]));
    // omega columns q, q+4 (transposed global reads, L1-hot)
    float oc0[8], oc1[8];
#pragma unroll
    for (int a = 0; a < 8; ++a) {
        oc0[a] = omega[mb + a * 8 + q];
        oc1[a] = omega[mb + a * 8 + q + 4];
    }
    // P = omega^T U (rows q, q+4)  (reuse s regs for P accumulation)
#pragma unroll
    for (int c = 0; c < 8; ++c) { s0[c] = 0.f; s1[c] = 0.f; }
#pragma unroll
    for (int a = 0; a < 8; ++a) {
        float Ua[8]; bcast_row(Ua, U0, U1, a);
#pragma unroll
        for (int c = 0; c < 8; ++c) {
            s0[c] = fmaf(oc0[a], Ua[c], s0[c]);
            s1[c] = fmaf(oc1[a], Ua[c], s1[c]);
        }
    }
    st_row(&sh_y[item][q * 8], s0);   // after this, sh_s region may be clobbered
    st_row(&sh_y[item][(q + 4) * 8], s1);

    if (q == 0) {
        float ldo = ldT - ldV;
        float a_i = 2.f * ldT - ld1;
        float s_j = ld1 - 2.f * ldo + cc - 8.0f;
        *(float4*)&sh_x[item][64] = make_float4(uf[0], uf[1], uf[2], uf[3]);
        *(float4*)&sh_x[item][68] = make_float4(uf[4], uf[5], uf[6], uf[7]);
        *(float4*)&sh_x[item][72] = make_float4(a_i, 1.f, 0.f, 0.f);
        *(float4*)&sh_y[item][64] =
            make_float4(-2.f * wf[0], -2.f * wf[1], -2.f * wf[2], -2.f * wf[3]);
        *(float4*)&sh_y[item][68] =
            make_float4(-2.f * wf[4], -2.f * wf[5], -2.f * wf[6], -2.f * wf[7]);
        *(float4*)&sh_y[item][72] = make_float4(1.f, s_j, 0.f, 0.f);
    }
    // single-wave workgroup: DS ops complete in program order; compiler
    // inserts lgkmcnt for RAW. Fence stops compile-time reordering.
    asm volatile("" ::: "memory");

    // ---- Phase 2: E[i,j] = 0.5 * dot76(x_i, y_j); 2i x 2j per lane ----
    {
        const int i0 = lane >> 3, j0 = lane & 7;
        const int i1 = i0 + 8, j1 = j0 + 8;
        const float4* x0 = (const float4*)&sh_x[i0][0];
        const float4* x1 = (const float4*)&sh_x[i1][0];
        const float4* y0 = (const float4*)&sh_y[j0][0];
        const float4* y1 = (const float4*)&sh_y[j1][0];
        float d00 = 0.f, d01 = 0.f, d10 = 0.f, d11 = 0.f;
#pragma unroll
        for (int k = 0; k < STR / 4; ++k) {
            float4 a0 = x0[k], a1 = x1[k], b0 = y0[k], b1 = y1[k];
            d00 = fmaf(a0.x, b0.x, d00); d00 = fmaf(a0.y, b0.y, d00);
            d00 = fmaf(a0.z, b0.z, d00); d00 = fmaf(a0.w, b0.w, d00);
            d01 = fmaf(a0.x, b1.x, d01); d01 = fmaf(a0.y, b1.y, d01);
            d01 = fmaf(a0.z, b1.z, d01); d01 = fmaf(a0.w, b1.w, d01);
            d10 = fmaf(a1.x, b0.x, d10); d10 = fmaf(a1.y, b0.y, d10);
            d10 = fmaf(a1.z, b0.z, d10); d10 = fmaf(a1.w, b0.w, d10);
            d11 = fmaf(a1.x, b1.x, d11); d11 = fmaf(a1.y, b1.y, d11);
            d11 = fmaf(a1.z, b1.z, d11); d11 = fmaf(a1.w, b1.w, d11);
        }
        const bool dg = (i0 == j0);
        out[(i0 * NN + j0) * GG + g] = dg ? 0.f : 0.5f * d00;
        out[(i0 * NN + j1) * GG + g] = 0.5f * d01;
        out[(i1 * NN + j0) * GG + g] = 0.5f * d10;
        out[(i1 * NN + j1) * GG + g] = dg ? 0.f : 0.5f * d11;
    }
}

extern "C" void kernel_launch(void* const* d_in, const int* in_sizes, int n_in,
                              void* d_out, int out_size, void* d_ws, size_t ws_size,
                              hipStream_t stream) {
    const float* omega = (const float*)d_in[0];
    const float* links = (const float*)d_in[1];
    const float* mu    = (const float*)d_in[2];
    const float* sigma = (const float*)d_in[3];
    float* out = (float*)d_out;
    hipLaunchKernelGGL(pairkl_kernel, dim3(NWG), dim3(64), 0, stream,
                       omega, links, mu, sigma, out);
}

// Round 14
// 26.216 us; speedup vs baseline: 1.1439x; 1.0155x over previous
//
#include <hip/hip_runtime.h>
#include <math.h>

#define NN 16
#define GG 4096
#define STR 76            // feature-vector stride (floats)
#define SSTR 68           // sigma stage stride (floats)
#define NWG GG            // 4096 blocks, 1 wave per block, 1 grid point per wave

#define LN2 0.6931471805599453f

__device__ __forceinline__ float frcp(float x) { return __builtin_amdgcn_rcpf(x); }
__device__ __forceinline__ float flogabs(float x) {
    return __builtin_amdgcn_logf(fabsf(x)) * LN2;
}

// ---- DPP helpers (quad_perm = VALU cross-lane, no DS pipe) ----
template <int CTRL>
__device__ __forceinline__ float dppf(float x) {
    return __builtin_bit_cast(float, __builtin_amdgcn_mov_dpp(
        __builtin_bit_cast(int, x), CTRL, 0xF, 0xF, true));
}
__device__ __forceinline__ float qb(float x, int L) {
    switch (L) {
        case 0:  return dppf<0x00>(x);
        case 1:  return dppf<0x55>(x);
        case 2:  return dppf<0xAA>(x);
        default: return dppf<0xFF>(x);
    }
}
__device__ __forceinline__ float qsum(float x) {
    x += dppf<0xB1>(x);  // perm[1,0,3,2]
    x += dppf<0x4E>(x);  // perm[2,3,0,1]
    return x;
}
__device__ __forceinline__ void bcast_row(float out[8], const float r0[8],
                                          const float r1[8], int k) {
#pragma unroll
    for (int c = 0; c < 8; ++c) {
        float s = (k < 4) ? r0[c] : r1[c];
        out[c] = qb(s, k & 3);
    }
}
__device__ __forceinline__ float sel_lo(const float r[8], int q) {
    return (q == 0) ? r[0] : (q == 1) ? r[1] : (q == 2) ? r[2] : r[3];
}
__device__ __forceinline__ float sel_hi(const float r[8], int q) {
    return (q == 0) ? r[4] : (q == 1) ? r[5] : (q == 2) ? r[6] : r[7];
}
__device__ __forceinline__ void ld_row(float r[8], const float* p) {
    float4 x = *(const float4*)p, y = *(const float4*)(p + 4);
    r[0] = x.x; r[1] = x.y; r[2] = x.z; r[3] = x.w;
    r[4] = y.x; r[5] = y.y; r[6] = y.z; r[7] = y.w;
}
__device__ __forceinline__ void st_row(float* p, const float r[8]) {
    *(float4*)p       = make_float4(r[0], r[1], r[2], r[3]);
    *(float4*)(p + 4) = make_float4(r[4], r[5], r[6], r[7]);
}
__device__ __forceinline__ float dot8(const float a[8], const float b[8]) {
    float s = a[0] * b[0];
    s = fmaf(a[1], b[1], s); s = fmaf(a[2], b[2], s);
    s = fmaf(a[3], b[3], s); s = fmaf(a[4], b[4], s);
    s = fmaf(a[5], b[5], s); s = fmaf(a[6], b[6], s);
    s = fmaf(a[7], b[7], s);
    return s;
}

// Fused 3-matrix elimination: full GJ inverse of T and S, LU det of V,
// interleaved so the three serial broadcast->rcp->update chains overlap.
// Lane q holds rows q (x0) and q+4 (x1) of each matrix. No pivoting.
__device__ __forceinline__ void elim3(float t0[8], float t1[8],
                                      float s0[8], float s1[8],
                                      float v0[8], float v1[8],
                                      float& ppT, float& ppS, float& ppV,
                                      int q) {
    ppT = 1.f; ppS = 1.f; ppV = 1.f;
#pragma unroll
    for (int k = 0; k < 8; ++k) {
        float Tk[8], Sk[8], Vk[8];
        bcast_row(Tk, t0, t1, k);
        bcast_row(Sk, s0, s1, k);
#pragma unroll
        for (int c = k; c < 8; ++c) {          // V: only cols >= k needed
            float sv = (k < 4) ? v0[c] : v1[c];
            Vk[c] = qb(sv, k & 3);
        }
        float pT = Tk[k], pS = Sk[k], pV = Vk[k];
        ppT *= pT; ppS *= pS; ppV *= pV;
        float iT = frcp(pT), iS = frcp(pS), iV = frcp(pV);
        const bool own0 = (k < 4) && (q == k);
        const bool own1 = (k >= 4) && (q == k - 4);
        float mT0 = -(own0 ? -1.0f : t0[k]) * iT;
        float mT1 = -(own1 ? -1.0f : t1[k]) * iT;
        float mS0 = -(own0 ? -1.0f : s0[k]) * iS;
        float mS1 = -(own1 ? -1.0f : s1[k]) * iS;
        float fV0 = (q > k) ? v0[k] * iV : 0.f;
        float fV1 = (q + 4 > k) ? v1[k] * iV : 0.f;
#pragma unroll
        for (int c = 0; c < 8; ++c) {
            float bT0 = own0 ? 0.0f : t0[c];
            float bT1 = own1 ? 0.0f : t1[c];
            t0[c] = fmaf(mT0, Tk[c], bT0);
            t1[c] = fmaf(mT1, Tk[c], bT1);
            float bS0 = own0 ? 0.0f : s0[c];
            float bS1 = own1 ? 0.0f : s1[c];
            s0[c] = fmaf(mS0, Sk[c], bS0);
            s1[c] = fmaf(mS1, Sk[c], bS1);
        }
        t0[k] = mT0; t1[k] = mT1;
        s0[k] = mS0; s1[k] = mS1;
#pragma unroll
        for (int c = k + 1; c < 8; ++c) {
            v0[c] = fmaf(-fV0, Vk[c], v0[c]);
            v1[c] = fmaf(-fV1, Vk[c], v1[c]);
        }
    }
}

__global__ __launch_bounds__(64) void pairkl_kernel(
    const float* __restrict__ omega, const float* __restrict__ links,
    const float* __restrict__ mu, const float* __restrict__ sigma,
    float* __restrict__ out) {
    __shared__ __align__(16) float sh_x[NN][STR];
    __shared__ __align__(16) float sh_y[NN][STR];
    // sigma stage overlaid on sh_y (15*68+64 = 1084 <= 1216 floats): every
    // sh_s read precedes every sh_y write in the single wave's program order,
    // and sh_s aliases sh_y so the compiler cannot reorder them.
    float* sh_s = &sh_y[0][0];  // layout [item][SSTR]

    const int bid  = blockIdx.x;
    const int g    = (bid & 7) * (NWG / 8) + (bid >> 3);  // XCD-bijective swizzle
    const int lane = threadIdx.x;
    const int item = lane >> 2;
    const int q    = lane & 3;
    const int mb   = (item * GG + g) * 64;

    // ---- Loads: V, omega, sigma to regs; sigma also staged to LDS ----
    float v0[8], v1[8], o0[8], o1[8], s0[8], s1[8], mq[8];
    {
        const float* l0p = links + ((item * 2 + 0) * GG + g) * 64;
        const float* l1p = links + ((item * 2 + 1) * GG + g) * 64;
        float la[8], lb[8];
        ld_row(la, l0p + q * 8);
        ld_row(lb, l1p + q * 8);
#pragma unroll
        for (int c = 0; c < 8; ++c) v0[c] = la[c] + lb[c] - ((c == q) ? 1.f : 0.f);
        ld_row(la, l0p + (q + 4) * 8);
        ld_row(lb, l1p + (q + 4) * 8);
#pragma unroll
        for (int c = 0; c < 8; ++c) v1[c] = la[c] + lb[c] - ((c == q + 4) ? 1.f : 0.f);
    }
    ld_row(o0, omega + mb + q * 8);
    ld_row(o1, omega + mb + (q + 4) * 8);
    ld_row(s0, sigma + mb + q * 8);
    ld_row(s1, sigma + mb + (q + 4) * 8);
    st_row(&sh_s[item * SSTR + q * 8], s0);
    st_row(&sh_s[item * SSTR + (q + 4) * 8], s1);
    ld_row(mq, mu + (item * GG + g) * 8);

    // ---- T = omega @ V ----
    float R0[8], R1[8];
#pragma unroll
    for (int c = 0; c < 8; ++c) { R0[c] = 0.f; R1[c] = 0.f; }
#pragma unroll
    for (int b = 0; b < 8; ++b) {
        float Vb[8]; bcast_row(Vb, v0, v1, b);
#pragma unroll
        for (int c = 0; c < 8; ++c) {
            R0[c] = fmaf(o0[b], Vb[c], R0[c]);
            R1[c] = fmaf(o1[b], Vb[c], R1[c]);
        }
    }

    // ---- Fused eliminations: R=T^{-1}, s=sigma^{-1}, det V ----
    float ppT, ppS, ppV;
    elim3(R0, R1, s0, s1, v0, v1, ppT, ppS, ppV, q);
    float ldT = flogabs(ppT);
    float ld1 = flogabs(ppS);
    float ldV = flogabs(ppV);

    // ---- Fused streams: Z = Winv @ sigma (LDS) || U = siginv @ omega (DPP) ----
    float Z0[8], Z1[8], U0[8], U1[8];
#pragma unroll
    for (int c = 0; c < 8; ++c) { Z0[c] = 0.f; Z1[c] = 0.f; U0[c] = 0.f; U1[c] = 0.f; }
#pragma unroll
    for (int b = 0; b < 8; ++b) {
        float sr[8]; ld_row(sr, &sh_s[item * SSTR + b * 8]);   // original sigma
        float Ob[8]; bcast_row(Ob, o0, o1, b);
#pragma unroll
        for (int c = 0; c < 8; ++c) {
            Z0[c] = fmaf(R0[b], sr[c], Z0[c]);
            Z1[c] = fmaf(R1[b], sr[c], Z1[c]);
            U0[c] = fmaf(s0[b], Ob[c], U0[c]);
            U1[c] = fmaf(s1[b], Ob[c], U1[c]);
        }
    }

    float u_lo = dot8(R0, mq), u_hi = dot8(R1, mq);
    float uf[8];
#pragma unroll
    for (int c = 0; c < 4; ++c) { uf[c] = qb(u_lo, c); uf[c + 4] = qb(u_hi, c); }
    float mql = sel_lo(mq, q), mqh = sel_hi(mq, q);
    float cc  = qsum(dot8(s0, mq) * mql + dot8(s1, mq) * mqh);
    float wf[8];
#pragma unroll
    for (int c = 0; c < 8; ++c) wf[c] = qsum(fmaf(mql, U0[c], mqh * U1[c]));

    // ---- X = Z Winv^T + u u^T  (reuse v regs) ----
#pragma unroll
    for (int c = 0; c < 8; ++c) {
        float Wc[8]; bcast_row(Wc, R0, R1, c);
        v0[c] = fmaf(u_lo, uf[c], dot8(Z0, Wc));
        v1[c] = fmaf(u_hi, uf[c], dot8(Z1, Wc));
    }
    st_row(&sh_x[item][q * 8], v0);
    st_row(&sh_x[item][(q + 4) * 8], v1);

    // ---- P = omega^T U  (omega columns from global, L1-hot; reuse s regs) ----
    float oc0[8], oc1[8];
#pragma unroll
    for (int a = 0; a < 8; ++a) {
        oc0[a] = omega[mb + a * 8 + q];
        oc1[a] = omega[mb + a * 8 + q + 4];
    }
#pragma unroll
    for (int c = 0; c < 8; ++c) { s0[c] = 0.f; s1[c] = 0.f; }
#pragma unroll
    for (int a = 0; a < 8; ++a) {
        float Ua[8]; bcast_row(Ua, U0, U1, a);
#pragma unroll
        for (int c = 0; c < 8; ++c) {
            s0[c] = fmaf(oc0[a], Ua[c], s0[c]);
            s1[c] = fmaf(oc1[a], Ua[c], s1[c]);
        }
    }
    st_row(&sh_y[item][q * 8], s0);   // after this, sh_s region may be clobbered
    st_row(&sh_y[item][(q + 4) * 8], s1);

    if (q == 0) {
        float ldo = ldT - ldV;
        float a_i = 2.f * ldT - ld1;
        float s_j = ld1 - 2.f * ldo + cc - 8.0f;
        *(float4*)&sh_x[item][64] = make_float4(uf[0], uf[1], uf[2], uf[3]);
        *(float4*)&sh_x[item][68] = make_float4(uf[4], uf[5], uf[6], uf[7]);
        *(float4*)&sh_x[item][72] = make_float4(a_i, 1.f, 0.f, 0.f);
        *(float4*)&sh_y[item][64] =
            make_float4(-2.f * wf[0], -2.f * wf[1], -2.f * wf[2], -2.f * wf[3]);
        *(float4*)&sh_y[item][68] =
            make_float4(-2.f * wf[4], -2.f * wf[5], -2.f * wf[6], -2.f * wf[7]);
        *(float4*)&sh_y[item][72] = make_float4(1.f, s_j, 0.f, 0.f);
    }
    // single-wave workgroup: DS ops complete in program order; compiler
    // inserts lgkmcnt for RAW. Fence stops compile-time reordering.
    asm volatile("" ::: "memory");

    // ---- Phase 2: E[i,j] = 0.5 * dot76(x_i, y_j); 2i x 2j per lane ----
    {
        const int i0 = lane >> 3, j0 = lane & 7;
        const int i1 = i0 + 8, j1 = j0 + 8;
        const float4* x0 = (const float4*)&sh_x[i0][0];
        const float4* x1 = (const float4*)&sh_x[i1][0];
        const float4* y0 = (const float4*)&sh_y[j0][0];
        const float4* y1 = (const float4*)&sh_y[j1][0];
        float d00 = 0.f, d01 = 0.f, d10 = 0.f, d11 = 0.f;
#pragma unroll
        for (int k = 0; k < STR / 4; ++k) {
            float4 a0 = x0[k], a1 = x1[k], b0 = y0[k], b1 = y1[k];
            d00 = fmaf(a0.x, b0.x, d00); d00 = fmaf(a0.y, b0.y, d00);
            d00 = fmaf(a0.z, b0.z, d00); d00 = fmaf(a0.w, b0.w, d00);
            d01 = fmaf(a0.x, b1.x, d01); d01 = fmaf(a0.y, b1.y, d01);
            d01 = fmaf(a0.z, b1.z, d01); d01 = fmaf(a0.w, b1.w, d01);
            d10 = fmaf(a1.x, b0.x, d10); d10 = fmaf(a1.y, b0.y, d10);
            d10 = fmaf(a1.z, b0.z, d10); d10 = fmaf(a1.w, b0.w, d10);
            d11 = fmaf(a1.x, b1.x, d11); d11 = fmaf(a1.y, b1.y, d11);
            d11 = fmaf(a1.z, b1.z, d11); d11 = fmaf(a1.w, b1.w, d11);
        }
        const bool dg = (i0 == j0);
        out[(i0 * NN + j0) * GG + g] = dg ? 0.f : 0.5f * d00;
        out[(i0 * NN + j1) * GG + g] = 0.5f * d01;
        out[(i1 * NN + j0) * GG + g] = 0.5f * d10;
        out[(i1 * NN + j1) * GG + g] = dg ? 0.f : 0.5f * d11;
    }
}

extern "C" void kernel_launch(void* const* d_in, const int* in_sizes, int n_in,
                              void* d_out, int out_size, void* d_ws, size_t ws_size,
                              hipStream_t stream) {
    const float* omega = (const float*)d_in[0];
    const float* links = (const float*)d_in[1];
    const float* mu    = (const float*)d_in[2];
    const float* sigma = (const float*)d_in[3];
    float* out = (float*)d_out;
    hipLaunchKernelGGL(pairkl_kernel, dim3(NWG), dim3(64), 0, stream,
                       omega, links, mu, sigma, out);
}